// Round 1
// baseline (469.698 us; speedup 1.0000x reference)
//
#include <hip/hip_runtime.h>

// RRF2d: y[b,o,p] = sum_l patches[b,l,p] * W[o,l,p] + bias[o,p]
// B=32, C_IN=32, H=W=64, K=3 pad=1, C_OUT=64, L=4096, KL = C_IN*9 = 288
//
// Thread tile: 8 batches x 8 out-channels, one spatial position p per thread.
// Block: 64 lanes (w) x 4 waves (b-chunks of 8) => all 32 batches in one block
//        so each weight cache line is fetched from HBM once (L1 reuse by waves).
// Grid:  64 rows (h) x 8 o-blocks (8 o's each).

#define B_SZ   32
#define C_IN   32
#define H_SZ   64
#define W_SZ   64
#define C_OUT  64
#define L_SZ   4096
#define KL     288

__global__ __launch_bounds__(256, 2)
void rrf2d_kernel(const float* __restrict__ x,
                  const float* __restrict__ wgt,
                  const float* __restrict__ bias,
                  float* __restrict__ out) {
    const int w  = threadIdx.x;            // 0..63  (spatial col)
    const int h  = blockIdx.x;             // 0..63  (spatial row)
    const int p  = h * W_SZ + w;           // spatial index
    const int b0 = threadIdx.y * 8;        // batch chunk base (wave-uniform)
    const int o0 = blockIdx.y * 8;         // out-channel base

    float acc[8][8];
#pragma unroll
    for (int i = 0; i < 8; ++i)
#pragma unroll
        for (int j = 0; j < 8; ++j) acc[i][j] = 0.f;

    // W[o, l, p]: stride per o = KL*L, per l = L. Base is wave-uniform except p.
    const float* wbase = wgt + (size_t)o0 * KL * L_SZ + p;

    for (int c = 0; c < C_IN; ++c) {
        const float* xc = x + ((size_t)b0 * C_IN + c) * (H_SZ * W_SZ);
#pragma unroll
        for (int dh = 0; dh < 3; ++dh) {
            const int row = h + dh - 1;
            if (row < 0 || row >= H_SZ) continue;   // uniform branch (h uniform)
            const float* xrow = xc + row * W_SZ;
#pragma unroll
            for (int dw = 0; dw < 3; ++dw) {
                const int l   = c * 9 + dh * 3 + dw;
                const int col = w + dw - 1;
                const bool v  = ((unsigned)col < (unsigned)W_SZ);
                const int colc = v ? col : 0;

                float xv[8];
#pragma unroll
                for (int i = 0; i < 8; ++i) {
                    float t = xrow[(size_t)i * (C_IN * H_SZ * W_SZ) + colc];
                    xv[i] = v ? t : 0.f;
                }

                const float* wl = wbase + (size_t)l * L_SZ;
                float wv[8];
#pragma unroll
                for (int j = 0; j < 8; ++j)
                    wv[j] = wl[(size_t)j * (KL * L_SZ)];

#pragma unroll
                for (int i = 0; i < 8; ++i)
#pragma unroll
                    for (int j = 0; j < 8; ++j)
                        acc[i][j] = fmaf(xv[i], wv[j], acc[i][j]);
            }
        }
    }

    float bv[8];
#pragma unroll
    for (int j = 0; j < 8; ++j)
        bv[j] = bias[(size_t)(o0 + j) * L_SZ + p];

#pragma unroll
    for (int i = 0; i < 8; ++i)
#pragma unroll
        for (int j = 0; j < 8; ++j)
            out[((size_t)(b0 + i) * C_OUT + (o0 + j)) * L_SZ + p] = acc[i][j] + bv[j];
}

extern "C" void kernel_launch(void* const* d_in, const int* in_sizes, int n_in,
                              void* d_out, int out_size, void* d_ws, size_t ws_size,
                              hipStream_t stream) {
    const float* x    = (const float*)d_in[0];
    const float* wgt  = (const float*)d_in[1];
    const float* bias = (const float*)d_in[2];
    float* out        = (float*)d_out;

    dim3 block(64, 4);   // 4 waves: b-chunks 0..7, 8..15, 16..23, 24..31
    dim3 grid(H_SZ, C_OUT / 8);  // 64 rows x 8 o-blocks

    hipLaunchKernelGGL(rrf2d_kernel, grid, block, 0, stream, x, wgt, bias, out);
}

// Round 2
// 321.082 us; speedup vs baseline: 1.4629x; 1.4629x over previous
//
#include <hip/hip_runtime.h>

// RRF2d: y[b,o,p] = sum_l patches[b,l,p] * W[o,l,p] + bias[o,p]
// B=32, C_IN=32, H=W=64, K=3 pad=1, C_OUT=64, L=4096, KL=288
//
// Thread tile: 2p (float2) x 4o x 8b. Block = 64 lanes x 4 waves (b-chunks)
// => all 32 batches per block, so each weight byte leaves HBM exactly once.
// Grid = 32 p-blocks (2 rows each) x 16 o-blocks = 512 blocks.

#define B_SZ   32
#define C_IN   32
#define H_SZ   64
#define W_SZ   64
#define C_OUT  64
#define L_SZ   4096
#define KL     288
#define XCH    (H_SZ * W_SZ)      // floats per (b,c) image

__global__ __launch_bounds__(256, 3)
void rrf2d_kernel(const float* __restrict__ x,
                  const float* __restrict__ wgt,
                  const float* __restrict__ bias,
                  float* __restrict__ out) {
    const int t  = threadIdx.x;          // 0..63
    const int rb = t >> 5;               // row within p-block: 0/1
    const int c0 = (t & 31) * 2;         // col base (even)
    const int h0 = blockIdx.x * 2;       // 2 rows per block
    const int o0 = blockIdx.y * 4;       // 4 out-channels per block
    const int b0 = threadIdx.y * 8;      // 8 batches per wave
    const int p  = (h0 + rb) * W_SZ + c0;

    float2 acc[8][4];
#pragma unroll
    for (int i = 0; i < 8; ++i)
#pragma unroll
        for (int j = 0; j < 4; ++j) { acc[i][j].x = 0.f; acc[i][j].y = 0.f; }

    const float* wbase = wgt + (size_t)o0 * (KL * L_SZ) + p;

    for (int c = 0; c < C_IN; ++c) {
        const float* xb = x + ((size_t)b0 * C_IN + c) * XCH;
#pragma unroll
        for (int dh = 0; dh < 3; ++dh) {
            const int row  = h0 + rb + dh - 1;                 // per-lane
            const bool rv  = ((unsigned)row < (unsigned)H_SZ);
            const int rowc = row < 0 ? 0 : (row > H_SZ - 1 ? H_SZ - 1 : row);
            const int roff = rowc * W_SZ;
            const bool lv  = rv && (c0 > 0);
            const bool rvv = rv && (c0 < W_SZ - 2);
            const int  loff = (c0 > 0) ? c0 - 1 : 0;
            const int  roff2 = (c0 < W_SZ - 2) ? c0 + 2 : W_SZ - 1;

            // staged x per b: [xl, x0, x1, xr] = cols c0-1 .. c0+2 (masked)
            float xs[8][4];
#pragma unroll
            for (int i = 0; i < 8; ++i) {
                const float* xr_ = xb + (size_t)i * (C_IN * XCH) + roff;
                const float2 xc2 = *(const float2*)(xr_ + c0);
                const float  xl  = xr_[loff];
                const float  xrg = xr_[roff2];
                xs[i][0] = lv  ? xl    : 0.f;
                xs[i][1] = rv  ? xc2.x : 0.f;
                xs[i][2] = rv  ? xc2.y : 0.f;
                xs[i][3] = rvv ? xrg   : 0.f;
            }
#pragma unroll
            for (int dw = 0; dw < 3; ++dw) {
                const int l = c * 9 + dh * 3 + dw;
                const float* wl = wbase + (size_t)l * L_SZ;
                float2 wv[4];
#pragma unroll
                for (int j = 0; j < 4; ++j)
                    wv[j] = *(const float2*)(wl + (size_t)j * (KL * L_SZ));
#pragma unroll
                for (int i = 0; i < 8; ++i)
#pragma unroll
                    for (int j = 0; j < 4; ++j) {
                        acc[i][j].x = fmaf(xs[i][dw],     wv[j].x, acc[i][j].x);
                        acc[i][j].y = fmaf(xs[i][dw + 1], wv[j].y, acc[i][j].y);
                    }
            }
        }
    }

#pragma unroll
    for (int j = 0; j < 4; ++j) {
        const float2 bv = *(const float2*)(bias + (size_t)(o0 + j) * L_SZ + p);
#pragma unroll
        for (int i = 0; i < 8; ++i) {
            float2 r;
            r.x = acc[i][j].x + bv.x;
            r.y = acc[i][j].y + bv.y;
            *(float2*)(out + ((size_t)(b0 + i) * C_OUT + (o0 + j)) * L_SZ + p) = r;
        }
    }
}

extern "C" void kernel_launch(void* const* d_in, const int* in_sizes, int n_in,
                              void* d_out, int out_size, void* d_ws, size_t ws_size,
                              hipStream_t stream) {
    const float* x    = (const float*)d_in[0];
    const float* wgt  = (const float*)d_in[1];
    const float* bias = (const float*)d_in[2];
    float* out        = (float*)d_out;

    dim3 block(64, 4);                       // 4 waves = 4 b-chunks of 8
    dim3 grid(H_SZ / 2, C_OUT / 4);          // 32 p-blocks x 16 o-blocks

    hipLaunchKernelGGL(rrf2d_kernel, grid, block, 0, stream, x, wgt, bias, out);
}

// Round 3
// 245.043 us; speedup vs baseline: 1.9168x; 1.3103x over previous
//
#include <hip/hip_runtime.h>

// RRF2d: y[b,o,p] = sum_l patches[b,l,p] * W[o,l,p] + bias[o,p]
// B=32, C_IN=32, H=W=64, K=3 pad=1, C_OUT=64, L=4096, KL=288
//
// Thread tile: 2p (float2 cols) x 2o x 8b = 32 acc.
// Block (64,4): 4 waves = 4 b-chunks => all 32 batches per block, so each
// weight byte leaves HBM exactly once. Halo cols come from neighbor lanes
// via __shfl (image-edge lanes masked to the zero pad).
// Grid = 32 p-blocks (2 rows) x 32 o-blocks = 1024 blocks = 4/CU = 16 waves/CU.

#define B_SZ   32
#define C_IN   32
#define H_SZ   64
#define W_SZ   64
#define C_OUT  64
#define L_SZ   4096
#define KL     288
#define XCH    (H_SZ * W_SZ)

__global__ __launch_bounds__(256, 4)
void rrf2d_kernel(const float* __restrict__ x,
                  const float* __restrict__ wgt,
                  const float* __restrict__ bias,
                  float* __restrict__ out) {
    const int t  = threadIdx.x;          // 0..63
    const int rb = t >> 5;               // row within block: 0/1
    const int k  = t & 31;               // col-pair index
    const int c0 = k * 2;                // col base
    const int h0 = blockIdx.x * 2;
    const int o0 = blockIdx.y * 2;
    const int b0 = threadIdx.y * 8;
    const int h  = h0 + rb;
    const int p  = h * W_SZ + c0;

    // per-dh tap-row offsets (clamped) + validity; hoisted out of c-loop
    int  roff[3];
    float rvm[3];
    #pragma unroll
    for (int dh = 0; dh < 3; ++dh) {
        const int r  = h + dh - 1;
        rvm[dh] = ((unsigned)r < (unsigned)H_SZ) ? 1.f : 0.f;
        const int rc = r < 0 ? 0 : (r > H_SZ - 1 ? H_SZ - 1 : r);
        roff[dh] = rc * W_SZ + c0;
    }
    const bool lval = (k != 0);          // left halo exists (else image pad=0)
    const bool rval = (k != 31);         // right halo exists
    const int  tl   = (t == 0)  ? 0  : t - 1;
    const int  tr   = (t == 63) ? 63 : t + 1;

    float2 acc[8][2];
    #pragma unroll
    for (int i = 0; i < 8; ++i)
        #pragma unroll
        for (int j = 0; j < 2; ++j) { acc[i][j].x = 0.f; acc[i][j].y = 0.f; }

    const float* wp = wgt + (size_t)o0 * (KL * L_SZ) + p;   // l = 0

    for (int c = 0; c < C_IN; ++c) {
        #pragma unroll
        for (int dh = 0; dh < 3; ++dh) {
            // weights for (c,dh): 3 dw x 2 o, dwordx2 each
            float2 wv[3][2];
            #pragma unroll
            for (int dw = 0; dw < 3; ++dw) {
                const float* wl = wp + (size_t)(dh * 3 + dw) * L_SZ;
                wv[dw][0] = *(const float2*)(wl);
                wv[dw][1] = *(const float2*)(wl + (size_t)KL * L_SZ);
            }

            // x tap-row for all 8 b: aligned float2 + halo via shuffle
            float xs[8][4];
            #pragma unroll
            for (int i = 0; i < 8; ++i) {
                const float* xr_ = x + ((size_t)(b0 + i) * C_IN + c) * XCH + roff[dh];
                float2 v = *(const float2*)xr_;
                v.x *= rvm[dh];
                v.y *= rvm[dh];
                const float xl = __shfl(v.y, tl);
                const float xr = __shfl(v.x, tr);
                xs[i][0] = lval ? xl : 0.f;
                xs[i][1] = v.x;
                xs[i][2] = v.y;
                xs[i][3] = rval ? xr : 0.f;
            }

            // FMAs: 8b x 3dw x 2o x 2cols = 96 per (c,dh)
            #pragma unroll
            for (int i = 0; i < 8; ++i)
                #pragma unroll
                for (int dw = 0; dw < 3; ++dw) {
                    acc[i][0].x = fmaf(xs[i][dw],     wv[dw][0].x, acc[i][0].x);
                    acc[i][0].y = fmaf(xs[i][dw + 1], wv[dw][0].y, acc[i][0].y);
                    acc[i][1].x = fmaf(xs[i][dw],     wv[dw][1].x, acc[i][1].x);
                    acc[i][1].y = fmaf(xs[i][dw + 1], wv[dw][1].y, acc[i][1].y);
                }
        }
        wp += 9 * L_SZ;   // next c (l += 9)
    }

    #pragma unroll
    for (int j = 0; j < 2; ++j) {
        const float2 bv = *(const float2*)(bias + (size_t)(o0 + j) * L_SZ + p);
        #pragma unroll
        for (int i = 0; i < 8; ++i) {
            float2 r;
            r.x = acc[i][j].x + bv.x;
            r.y = acc[i][j].y + bv.y;
            *(float2*)(out + ((size_t)(b0 + i) * C_OUT + (o0 + j)) * L_SZ + p) = r;
        }
    }
}

extern "C" void kernel_launch(void* const* d_in, const int* in_sizes, int n_in,
                              void* d_out, int out_size, void* d_ws, size_t ws_size,
                              hipStream_t stream) {
    const float* x    = (const float*)d_in[0];
    const float* wgt  = (const float*)d_in[1];
    const float* bias = (const float*)d_in[2];
    float* out        = (float*)d_out;

    dim3 block(64, 4);                        // 4 waves = 4 b-chunks of 8
    dim3 grid(H_SZ / 2, C_OUT / 2);           // 32 p-blocks x 32 o-blocks = 1024

    hipLaunchKernelGGL(rrf2d_kernel, grid, block, 0, stream, x, wgt, bias, out);
}

// Round 4
// 162.621 us; speedup vs baseline: 2.8883x; 1.5068x over previous
//
#include <hip/hip_runtime.h>

// RRF2d: y[b,o,p] = sum_l patches[b,l,p] * W[o,l,p] + bias[o,p]
// B=32, C_IN=32, H=W=64, K=3 pad=1, C_OUT=64, L=4096, KL=288
//
// R4: weights streamed HBM -> LDS via global_load_lds, double-buffered per c
// (9 KB per buffer: 9 taps x 2 o x 128 p), counted vmcnt(9) + raw s_barrier
// so the next-c prefetch stays in flight across the barrier (T3/T4 pattern).
// Block (64,4): 4 waves = 4 b-chunks => all 32 batches per block (weights
// leave HBM exactly once). Thread tile: 2 cols (float2) x 2 o x 8 b.
// Grid = 32 p-blocks (2 rows) x 32 o-blocks = 1024 blocks = 4/CU.

#define C_IN   32
#define H_SZ   64
#define W_SZ   64
#define C_OUT  64
#define L_SZ   4096
#define KL     288
#define XCH    (H_SZ * W_SZ)

__device__ __forceinline__ void gload_lds4(const float* g, float* l) {
    __builtin_amdgcn_global_load_lds(
        (const __attribute__((address_space(1))) void*)g,
        (__attribute__((address_space(3))) void*)l, 4, 0, 0);
}

__global__ __launch_bounds__(256, 4)
void rrf2d_kernel(const float* __restrict__ x,
                  const float* __restrict__ wgt,
                  const float* __restrict__ bias,
                  float* __restrict__ out) {
    __shared__ float wlds[2][9 * 2 * 128];   // [buf][ (j*2+o)*128 + p_local ]

    const int t   = threadIdx.x;                                  // lane 0..63
    const int wyu = __builtin_amdgcn_readfirstlane(threadIdx.y);  // wave 0..3
    const int rb  = t >> 5;
    const int k   = t & 31;
    const int c0  = k * 2;
    const int h0  = blockIdx.x * 2;
    const int o0  = blockIdx.y * 2;
    const int b0  = wyu * 8;
    const int h   = h0 + rb;
    const int p   = h * W_SZ + c0;
    const int pl  = rb * 64 + c0;            // p_local within block (0..127)
    const int p0  = h0 * W_SZ;               // block p base

    // per-dh tap rows (clamped) + validity mask
    int roff[3]; float rvm[3];
    #pragma unroll
    for (int dh = 0; dh < 3; ++dh) {
        const int r = h + dh - 1;
        rvm[dh] = ((unsigned)r < (unsigned)H_SZ) ? 1.f : 0.f;
        const int rc = r < 0 ? 0 : (r > H_SZ - 1 ? H_SZ - 1 : r);
        roff[dh] = rc * W_SZ + c0;
    }
    const bool lval = (k != 0), rval = (k != 31);
    const int  tl = (t == 0) ? 0 : t - 1;
    const int  tr = (t == 63) ? 63 : t + 1;

    float2 acc[8][2];
    #pragma unroll
    for (int i = 0; i < 8; ++i)
        #pragma unroll
        for (int j = 0; j < 2; ++j) { acc[i][j].x = 0.f; acc[i][j].y = 0.f; }

    // Uniform (SGPR) staging base offsets; this wave's 9 pieces are
    // r = wyu*9 + s, with r -> j = r>>2, o = (r>>1)&1, q = r&1.
    const size_t obase[2] = { (size_t)o0 * (KL * (size_t)L_SZ) + p0,
                              (size_t)(o0 + 1) * (KL * (size_t)L_SZ) + p0 };

    // stage weights for channel cc into wlds[cc&1]: 9 DMA calls per wave
    auto stage = [&](int cc) {
        float* dst = wlds[cc & 1];
        const size_t coff = (size_t)cc * 9 * L_SZ;
        #pragma unroll
        for (int s = 0; s < 9; ++s) {
            const int r = wyu * 9 + s;
            const int j = r >> 2, o = (r >> 1) & 1, q = r & 1;
            const float* g = wgt + obase[o] + coff + (size_t)j * L_SZ + q * 64 + t;
            gload_lds4(g, dst + (j * 2 + o) * 128 + q * 64);
        }
    };

    // prologue: stage c=0, full drain
    stage(0);
    asm volatile("s_waitcnt vmcnt(0)" ::: "memory");
    __builtin_amdgcn_s_barrier();
    __builtin_amdgcn_sched_barrier(0);

    for (int c = 0; c < C_IN; ++c) {
        // issue next-c prefetch, then wait for THIS c's staging only
        if (c + 1 < C_IN) {
            stage(c + 1);
            asm volatile("s_waitcnt vmcnt(9)" ::: "memory");
        } else {
            asm volatile("s_waitcnt vmcnt(0)" ::: "memory");
        }
        __builtin_amdgcn_s_barrier();          // all waves' DMA(c) complete
        __builtin_amdgcn_sched_barrier(0);

        const float* wb  = wlds[c & 1];
        const float* xco = x + (size_t)c * XCH;

        #pragma unroll
        for (int dh = 0; dh < 3; ++dh) {
            // weights from LDS: 3 dw x 2 o, ds_read_b64 each
            float2 wv[3][2];
            #pragma unroll
            for (int dw = 0; dw < 3; ++dw) {
                const int j = dh * 3 + dw;
                wv[dw][0] = *(const float2*)(wb + (j * 2 + 0) * 128 + pl);
                wv[dw][1] = *(const float2*)(wb + (j * 2 + 1) * 128 + pl);
            }

            // x tap-row for 8 b: aligned float2 + halo via shuffle
            float xs[8][4];
            #pragma unroll
            for (int i = 0; i < 8; ++i) {
                const float* xr_ = xco + ((size_t)(b0 + i) * C_IN) * XCH + roff[dh];
                float2 v = *(const float2*)xr_;
                v.x *= rvm[dh];
                v.y *= rvm[dh];
                const float xl = __shfl(v.y, tl);
                const float xr = __shfl(v.x, tr);
                xs[i][0] = lval ? xl : 0.f;
                xs[i][1] = v.x;
                xs[i][2] = v.y;
                xs[i][3] = rval ? xr : 0.f;
            }

            // 8b x 3dw x 2o x 2cols = 96 FMAs
            #pragma unroll
            for (int i = 0; i < 8; ++i)
                #pragma unroll
                for (int dw = 0; dw < 3; ++dw) {
                    acc[i][0].x = fmaf(xs[i][dw],     wv[dw][0].x, acc[i][0].x);
                    acc[i][0].y = fmaf(xs[i][dw + 1], wv[dw][0].y, acc[i][0].y);
                    acc[i][1].x = fmaf(xs[i][dw],     wv[dw][1].x, acc[i][1].x);
                    acc[i][1].y = fmaf(xs[i][dw + 1], wv[dw][1].y, acc[i][1].y);
                }
        }
        __builtin_amdgcn_s_barrier();          // reads of wlds[c&1] done
    }

    #pragma unroll
    for (int j = 0; j < 2; ++j) {
        const float2 bv = *(const float2*)(bias + (size_t)(o0 + j) * L_SZ + p);
        #pragma unroll
        for (int i = 0; i < 8; ++i) {
            float2 r;
            r.x = acc[i][j].x + bv.x;
            r.y = acc[i][j].y + bv.y;
            *(float2*)(out + ((size_t)(b0 + i) * C_OUT + (o0 + j)) * L_SZ + p) = r;
        }
    }
}

extern "C" void kernel_launch(void* const* d_in, const int* in_sizes, int n_in,
                              void* d_out, int out_size, void* d_ws, size_t ws_size,
                              hipStream_t stream) {
    const float* x    = (const float*)d_in[0];
    const float* wgt  = (const float*)d_in[1];
    const float* bias = (const float*)d_in[2];
    float* out        = (float*)d_out;

    dim3 block(64, 4);                       // 4 waves = 4 b-chunks of 8
    dim3 grid(H_SZ / 2, C_OUT / 2);          // 1024 blocks

    hipLaunchKernelGGL(rrf2d_kernel, grid, block, 0, stream, x, wgt, bias, out);
}